// Round 6
// baseline (5576.080 us; speedup 1.0000x reference)
//
#include <hip/hip_runtime.h>
#include <hip/hip_bf16.h>

typedef __hip_bfloat16 bf16;
typedef __attribute__((ext_vector_type(8))) short short8;
typedef __attribute__((ext_vector_type(4))) float floatx4;

#define NNODES 118784
#define NEDGES 3000000
#define INDIM 116
#define EMBD 16
#define HID 64
#define NGRAPH 1024
#define ROIS 116
#define NBUCK 1856          // NNODES / 64

__device__ __forceinline__ float b2f(bf16 v) { return __bfloat162float(v); }
__device__ __forceinline__ bf16 f2b(float v) { return __float2bfloat16(v); }
__device__ __forceinline__ unsigned f2u(float v) {
    bf16 b = __float2bfloat16(v);
    return (unsigned)*reinterpret_cast<unsigned short*>(&b);
}

// ---------------------------------------------------------------------------
// Phase 1: per-bucket edge counts (counters padded to 64B lines)
// ---------------------------------------------------------------------------
__global__ __launch_bounds__(256) void count64_kernel(
    const int* __restrict__ dst, int* __restrict__ cnt64)
{
    const int i = (blockIdx.x * 256 + threadIdx.x) * 4;
    if (i + 3 < NEDGES) {
        int4 d = *(const int4*)(dst + i);
        atomicAdd(&cnt64[(d.x >> 6) * 16], 1);
        atomicAdd(&cnt64[(d.y >> 6) * 16], 1);
        atomicAdd(&cnt64[(d.z >> 6) * 16], 1);
        atomicAdd(&cnt64[(d.w >> 6) * 16], 1);
    }
}

// ---------------------------------------------------------------------------
// Phase 2: exclusive scan of 1856 bucket counts (single block)
// ---------------------------------------------------------------------------
__global__ __launch_bounds__(256) void scan64_kernel(
    const int* __restrict__ cnt64, int* __restrict__ off64)
{
    __shared__ int sums[256];
    const int t = threadIdx.x;
    int loc[8];
    int s = 0;
    #pragma unroll
    for (int j = 0; j < 8; j++) {
        const int idx = t * 8 + j;
        const int v = (idx < NBUCK) ? cnt64[idx * 16] : 0;
        loc[j] = s;
        s += v;
    }
    sums[t] = s;
    __syncthreads();
    for (int d = 1; d < 256; d <<= 1) {
        int v = (t >= d) ? sums[t - d] : 0;
        __syncthreads();
        sums[t] += v;
        __syncthreads();
    }
    const int base = (t == 0) ? 0 : sums[t - 1];
    #pragma unroll
    for (int j = 0; j < 8; j++) {
        const int idx = t * 8 + j;
        if (idx < NBUCK) off64[idx] = base + loc[j];
    }
    if (t == 255) off64[NBUCK] = sums[255];
}

// ---------------------------------------------------------------------------
// Phase 3: place packed records into exact bucket segments.
// record = {src | dlo<<17, ea0|ea1<<16, ea2|ea3<<16, ea4}  (16B)
// ---------------------------------------------------------------------------
__global__ __launch_bounds__(256) void place_kernel(
    const int* __restrict__ src, const int* __restrict__ dst,
    const float* __restrict__ ea, int* __restrict__ cur64,
    const int* __restrict__ off64, uint4* __restrict__ rec)
{
    const int e = blockIdx.x * 256 + threadIdx.x;
    if (e >= NEDGES) return;
    const int s = src[e], d = dst[e];
    const int b = d >> 6, dlo = d & 63;
    const float* a = ea + (size_t)e * 5;
    const unsigned m0 = f2u(a[0]) | (f2u(a[1]) << 16);
    const unsigned m1 = f2u(a[2]) | (f2u(a[3]) << 16);
    const unsigned m2 = f2u(a[4]);
    const unsigned meta = (unsigned)s | ((unsigned)dlo << 17);
    const int p = atomicAdd(&cur64[b * 16], 1);
    rec[off64[b] + p] = make_uint4(meta, m0, m1, m2);
}

// ---------------------------------------------------------------------------
// Encoder as MFMA GEMM (unchanged from round 5 — verified)
// ---------------------------------------------------------------------------
__global__ __launch_bounds__(256) void enc_kernel(
    const float* __restrict__ x, const int* __restrict__ gid,
    const float* __restrict__ emb, const float* __restrict__ Wenc,
    const float* __restrict__ benc,
    bf16* __restrict__ hb, float* __restrict__ stats)
{
    __shared__ unsigned short Ap[4 * 5 * 64 * 8];
    __shared__ unsigned short Bp[4 * 5 * 64 * 8];

    const int tid = threadIdx.x;
    const int r0 = blockIdx.x * 64;

    for (int i = tid; i < 64 * INDIM; i += 256) {
        const int r = i / INDIM, k = i - r * INDIM;
        const float v = x[(size_t)(r0 + r) * INDIM + k];
        const int g = r >> 4, m = r & 15, s = k >> 5, q = (k >> 3) & 3, j = k & 7;
        Ap[(((g * 5 + s) * 64) + q * 16 + m) * 8 + j] = (unsigned short)f2u(v);
    }
    for (int i = tid; i < 64 * EMBD; i += 256) {
        const int r = i >> 4, kk = i & 15, k = INDIM + kk;
        const float v = emb[gid[r0 + r] * EMBD + kk];
        const int g = r >> 4, m = r & 15, s = k >> 5, q = (k >> 3) & 3, j = k & 7;
        Ap[(((g * 5 + s) * 64) + q * 16 + m) * 8 + j] = (unsigned short)f2u(v);
    }
    for (int i = tid; i < 64 * 28; i += 256) {
        const int r = i / 28, k = 132 + (i - r * 28);
        const int g = r >> 4, m = r & 15, s = k >> 5, q = (k >> 3) & 3, j = k & 7;
        Ap[(((g * 5 + s) * 64) + q * 16 + m) * 8 + j] = 0;
    }
    for (int i = tid; i < 132 * 64; i += 256) {
        const int k = i >> 6, n = i & 63;
        const float v = Wenc[i];
        const int c = n >> 4, m = n & 15, s = k >> 5, q = (k >> 3) & 3, j = k & 7;
        Bp[(((c * 5 + s) * 64) + q * 16 + m) * 8 + j] = (unsigned short)f2u(v);
    }
    for (int i = tid; i < 28 * 64; i += 256) {
        const int k = 132 + (i >> 6), n = i & 63;
        const int c = n >> 4, m = n & 15, s = k >> 5, q = (k >> 3) & 3, j = k & 7;
        Bp[(((c * 5 + s) * 64) + q * 16 + m) * 8 + j] = 0;
    }
    __syncthreads();

    const int lane = tid & 63;
    const int wv   = tid >> 6;
    const int m    = lane & 15;
    const int q    = lane >> 4;

    floatx4 acc[4];
    #pragma unroll
    for (int c = 0; c < 4; c++) acc[c] = {0.f, 0.f, 0.f, 0.f};

    #pragma unroll
    for (int s = 0; s < 5; s++) {
        short8 af = *(const short8*)&Ap[((wv * 5 + s) * 64 + lane) * 8];
        #pragma unroll
        for (int c = 0; c < 4; c++) {
            short8 bfr = *(const short8*)&Bp[((c * 5 + s) * 64 + lane) * 8];
            acc[c] = __builtin_amdgcn_mfma_f32_16x16x32_bf16(af, bfr, acc[c], 0, 0, 0);
        }
    }

    #pragma unroll
    for (int c = 0; c < 4; c++) {
        const int ch = c * 16 + m;
        const float bb = benc[ch];
        float sv = 0.f, sq = 0.f;
        #pragma unroll
        for (int r = 0; r < 4; r++) {
            const int row = r0 + wv * 16 + q * 4 + r;
            float a = fmaxf(acc[c][r] + bb, 0.f);
            hb[(size_t)row * HID + ch] = f2b(a);
            sv += a; sq += a * a;
        }
        sv += __shfl_xor(sv, 16); sv += __shfl_xor(sv, 32);
        sq += __shfl_xor(sq, 16); sq += __shfl_xor(sq, 32);
        if (q == 0) {
            unsafeAtomicAdd(&stats[ch], sv);
            unsafeAtomicAdd(&stats[64 + ch], sq);
        }
    }
}

// ---------------------------------------------------------------------------
// Bucket aggregation with fused BN-on-read.
// MODE: 0 = identity, 1 = BN (no relu), 2 = BN + relu  (applied to hin reads)
// z[n] = T(h[n]) + sum_{e->n} relu(T(h[src]) + ea@We + be)
// ---------------------------------------------------------------------------
template <int MODE>
__global__ __launch_bounds__(256) void aggb_kernel(
    const bf16* __restrict__ hin, bf16* __restrict__ zout,
    const uint4* __restrict__ rec, const int* __restrict__ off64,
    const float* __restrict__ We, const float* __restrict__ be,
    const float* __restrict__ stats, const float* __restrict__ gamma,
    const float* __restrict__ beta)
{
    __shared__ float agg[64 * 64];   // 16 KB
    const int tid = threadIdx.x;
    const int lane = tid & 63;
    const int wv = tid >> 6;
    const int b = blockIdx.x;

    for (int i = tid; i < 4096; i += 256) agg[i] = 0.f;

    float gg = 1.f, bbt = 0.f;
    if (MODE != 0) {
        const float m = stats[lane] * (1.f / NNODES);
        const float var = stats[64 + lane] * (1.f / NNODES) - m * m;
        const float inv = rsqrtf(var + 1e-5f);
        gg = gamma[lane] * inv;
        bbt = beta[lane] - gg * m;
    }
    const float w0 = We[lane], w1 = We[64 + lane], w2 = We[128 + lane];
    const float w3 = We[192 + lane], w4 = We[256 + lane];
    const float bel = be[lane];
    __syncthreads();

    const int s0 = off64[b], s1 = off64[b + 1];

    auto proc = [&](int i) {
        const uint4 r = rec[i];
        const int src = r.x & 0x1FFFF;
        const int dlo = (r.x >> 17) & 63;
        float h = b2f(hin[(size_t)src * HID + lane]);
        if (MODE == 1) h = gg * h + bbt;
        if (MODE == 2) h = fmaxf(gg * h + bbt, 0.f);
        const float f0 = __uint_as_float(r.y << 16);
        const float f1 = __uint_as_float(r.y & 0xFFFF0000u);
        const float f2v = __uint_as_float(r.z << 16);
        const float f3 = __uint_as_float(r.z & 0xFFFF0000u);
        const float f4 = __uint_as_float(r.w << 16);
        const float v = bel + f0 * w0 + f1 * w1 + f2v * w2 + f3 * w3 + f4 * w4 + h;
        atomicAdd(&agg[dlo * 64 + lane], fmaxf(v, 0.f));
    };

    int i = s0 + wv;
    for (; i + 12 < s1; i += 16) { proc(i); proc(i + 4); proc(i + 8); proc(i + 12); }
    for (; i < s1; i += 4) proc(i);
    __syncthreads();

    #pragma unroll 4
    for (int r = 0; r < 16; r++) {
        const int nl = wv * 16 + r;
        const int n = b * 64 + nl;
        float h = b2f(hin[(size_t)n * HID + lane]);
        if (MODE == 1) h = gg * h + bbt;
        if (MODE == 2) h = fmaxf(gg * h + bbt, 0.f);
        zout[(size_t)n * HID + lane] = f2b(h + agg[nl * 64 + lane]);
    }
}

// ---------------------------------------------------------------------------
// Node MLP via MFMA, in place on Z (unchanged from round 5 — verified)
// MODE 0: z <- relu(o).  MODE 1: z <- o (pre-BN) + stats.
// ---------------------------------------------------------------------------
template <int MODE>
__global__ __launch_bounds__(256) void mlp_kernel(
    bf16* __restrict__ Zg,
    const float* __restrict__ W1, const float* __restrict__ b1,
    const float* __restrict__ W2, const float* __restrict__ b2,
    float* __restrict__ stats)
{
    __shared__ unsigned short Zl[64 * 72];
    __shared__ unsigned short W1t[64 * 72];
    __shared__ unsigned short W2t[64 * 72];
    __shared__ unsigned short Tl[64 * 72];

    const int tid = threadIdx.x;
    const int r0 = blockIdx.x * 64;

    for (int i = tid; i < 4096; i += 256) {
        int k = i >> 6, n = i & 63;
        W1t[n * 72 + k] = (unsigned short)f2u(W1[i]);
        W2t[n * 72 + k] = (unsigned short)f2u(W2[i]);
    }
    {
        const uint4* zg = (const uint4*)(Zg + (size_t)r0 * HID);
        for (int i = tid; i < 512; i += 256) {
            int row = i >> 3, ch = i & 7;
            uint4 v = zg[row * 8 + ch];
            *(uint4*)&Zl[row * 72 + ch * 8] = v;
        }
    }
    __syncthreads();

    const int lane = tid & 63;
    const int wv   = tid >> 6;
    const int m    = lane & 15;
    const int q    = lane >> 4;
    const int mrow = wv * 16;

    float bias1[4], bias2[4];
    #pragma unroll
    for (int c = 0; c < 4; c++) {
        bias1[c] = b1[c * 16 + m];
        bias2[c] = b2[c * 16 + m];
    }

    floatx4 acc[4];
    #pragma unroll
    for (int c = 0; c < 4; c++) acc[c] = {0.f, 0.f, 0.f, 0.f};
    #pragma unroll
    for (int s = 0; s < 2; s++) {
        short8 af = *(const short8*)&Zl[(mrow + m) * 72 + s * 32 + q * 8];
        #pragma unroll
        for (int c = 0; c < 4; c++) {
            short8 bfr = *(const short8*)&W1t[(c * 16 + m) * 72 + s * 32 + q * 8];
            acc[c] = __builtin_amdgcn_mfma_f32_16x16x32_bf16(af, bfr, acc[c], 0, 0, 0);
        }
    }
    #pragma unroll
    for (int c = 0; c < 4; c++)
        #pragma unroll
        for (int r = 0; r < 4; r++)
            Tl[(mrow + q * 4 + r) * 72 + c * 16 + m] =
                (unsigned short)f2u(fmaxf(acc[c][r] + bias1[c], 0.f));
    __syncthreads();

    #pragma unroll
    for (int c = 0; c < 4; c++) acc[c] = {0.f, 0.f, 0.f, 0.f};
    #pragma unroll
    for (int s = 0; s < 2; s++) {
        short8 af = *(const short8*)&Tl[(mrow + m) * 72 + s * 32 + q * 8];
        #pragma unroll
        for (int c = 0; c < 4; c++) {
            short8 bfr = *(const short8*)&W2t[(c * 16 + m) * 72 + s * 32 + q * 8];
            acc[c] = __builtin_amdgcn_mfma_f32_16x16x32_bf16(af, bfr, acc[c], 0, 0, 0);
        }
    }
    #pragma unroll
    for (int c = 0; c < 4; c++) {
        float sv = 0.f, sq = 0.f;
        #pragma unroll
        for (int r = 0; r < 4; r++) {
            float o = acc[c][r] + bias2[c];
            if (MODE == 0) o = fmaxf(o, 0.f);
            Zg[(size_t)(r0 + mrow + q * 4 + r) * HID + c * 16 + m] = f2b(o);
            if (MODE == 1) { sv += o; sq += o * o; }
        }
        if (MODE == 1) {
            sv += __shfl_xor(sv, 16); sv += __shfl_xor(sv, 32);
            sq += __shfl_xor(sq, 16); sq += __shfl_xor(sq, 32);
            if (q == 0) {
                unsafeAtomicAdd(&stats[c * 16 + m], sv);
                unsafeAtomicAdd(&stats[64 + c * 16 + m], sq);
            }
        }
    }
}

// ---------------------------------------------------------------------------
// Head with fused final BN+relu: pooled = seg-sum of max(gg*h+bb,0)
// ---------------------------------------------------------------------------
__global__ __launch_bounds__(128) void head_kernel(
    const bf16* __restrict__ hb, const float* __restrict__ Wl1,
    const float* __restrict__ bl1, const float* __restrict__ Wl2,
    const float* __restrict__ bl2, float* __restrict__ out,
    const float* __restrict__ stats, const float* __restrict__ gamma,
    const float* __restrict__ beta)
{
    __shared__ float part[2 * HID];
    __shared__ float ps[HID];
    __shared__ float r0[128], r1[128];

    const int g = blockIdx.x;
    const int tid = threadIdx.x;
    const int lane = tid & 63;
    const int wv = tid >> 6;
    const bf16* hbg = hb + (size_t)g * ROIS * HID;

    const float mm = stats[lane] * (1.f / NNODES);
    const float var = stats[64 + lane] * (1.f / NNODES) - mm * mm;
    const float inv = rsqrtf(var + 1e-5f);
    const float gg = gamma[lane] * inv;
    const float bbt = beta[lane] - gg * mm;

    float acc = 0.f;
    for (int r = wv; r < ROIS; r += 2)
        acc += fmaxf(gg * b2f(hbg[r * HID + lane]) + bbt, 0.f);
    part[wv * HID + lane] = acc;
    __syncthreads();
    if (tid < HID) ps[tid] = fmaxf(part[tid] + part[HID + tid], 0.f);
    __syncthreads();

    float e0 = 0.f, e1 = 0.f;
    if (tid < ROIS) {
        float a = bl1[tid];
        #pragma unroll 8
        for (int c = 0; c < HID; c++)
            a += ps[c] * Wl1[c * ROIS + tid];
        e0 = a * Wl2[tid * 2 + 0];
        e1 = a * Wl2[tid * 2 + 1];
    }
    r0[tid] = e0;
    r1[tid] = e1;
    __syncthreads();
    for (int s = 64; s > 0; s >>= 1) {
        if (tid < s) { r0[tid] += r0[tid + s]; r1[tid] += r1[tid + s]; }
        __syncthreads();
    }
    if (tid == 0) {
        out[g * 2 + 0] = r0[0] + bl2[0];
        out[g * 2 + 1] = r1[0] + bl2[1];
    }
}

// ---------------------------------------------------------------------------
extern "C" void kernel_launch(void* const* d_in, const int* in_sizes, int n_in,
                              void* d_out, int out_size, void* d_ws, size_t ws_size,
                              hipStream_t stream)
{
    const float* x       = (const float*)d_in[0];
    const float* ea      = (const float*)d_in[1];
    const int*   eidx    = (const int*)  d_in[2];
    const int*   gid     = (const int*)  d_in[4];
    const float* emb     = (const float*)d_in[5];
    const float* Wenc    = (const float*)d_in[6];
    const float* benc    = (const float*)d_in[7];
    const float* gamma_e = (const float*)d_in[8];
    const float* beta_e  = (const float*)d_in[9];
    const float* We0     = (const float*)d_in[10];
    const float* be0     = (const float*)d_in[11];
    const float* W10     = (const float*)d_in[12];
    const float* b10     = (const float*)d_in[13];
    const float* W20     = (const float*)d_in[14];
    const float* b20     = (const float*)d_in[15];
    const float* We      = (const float*)d_in[16];
    const float* be      = (const float*)d_in[17];
    const float* W1      = (const float*)d_in[18];
    const float* b1      = (const float*)d_in[19];
    const float* W2      = (const float*)d_in[20];
    const float* b2      = (const float*)d_in[21];
    const float* gamma   = (const float*)d_in[22];
    const float* beta    = (const float*)d_in[23];
    const float* Wl1     = (const float*)d_in[24];
    const float* bl1     = (const float*)d_in[25];
    const float* Wl2     = (const float*)d_in[26];
    const float* bl2     = (const float*)d_in[27];

    const int* srcp = eidx;
    const int* dstp = eidx + NEDGES;

    // workspace (~78.7 MB):
    // A (bf16 NH) | Z (bf16 NH) | rec (16B * E) | cnt64 | cur64 | off64 | stats
    const size_t NH = (size_t)NNODES * HID;
    char* p = (char*)d_ws;
    bf16*  Abuf = (bf16*)p;  p += NH * 2;
    bf16*  Zbuf = (bf16*)p;  p += NH * 2;
    uint4* rec  = (uint4*)p; p += (size_t)NEDGES * 16;
    int* cnt64  = (int*)p;   p += (size_t)NBUCK * 16 * 4;
    int* cur64  = (int*)p;   p += (size_t)NBUCK * 16 * 4;
    int* off64  = (int*)p;   p += (size_t)(NBUCK + 16) * 4;
    float* stats = (float*)p;                    // 512 floats

    hipMemsetAsync(cnt64, 0, (size_t)NBUCK * 16 * 4 * 2, stream);  // cnt64+cur64
    hipMemsetAsync(stats, 0, 512 * 4, stream);

    const int eb = (NEDGES + 255) / 256;          // 11719
    const int cb = (NEDGES / 4 + 255) / 256;      // 2930

    // ---- bucket the edges (by dst >> 6) ----
    count64_kernel<<<cb, 256, 0, stream>>>(dstp, cnt64);
    scan64_kernel<<<1, 256, 0, stream>>>(cnt64, off64);
    place_kernel<<<eb, 256, 0, stream>>>(srcp, dstp, ea, cur64, off64, rec);

    // ---- encoder (pre-BN + stats0) ----
    enc_kernel<<<NBUCK, 256, 0, stream>>>(x, gid, emb, Wenc, benc, Abuf, stats);

    // ---- GINE layer 0: T = BN_e (no relu) on A reads; mlp relu ----
    aggb_kernel<1><<<NBUCK, 256, 0, stream>>>(Abuf, Zbuf, rec, off64, We0, be0,
                                              stats, gamma_e, beta_e);
    mlp_kernel<0><<<NBUCK, 256, 0, stream>>>(Zbuf, W10, b10, W20, b20, nullptr);

    // ---- GINE layer 1: identity transform (input already relu'd) ----
    aggb_kernel<0><<<NBUCK, 256, 0, stream>>>(Zbuf, Abuf, rec, off64, We, be,
                                              nullptr, nullptr, nullptr);
    mlp_kernel<1><<<NBUCK, 256, 0, stream>>>(Abuf, W1, b1, W2, b2, stats + 128);

    // ---- GINE layer 2: T = BN+relu with stats1 ----
    aggb_kernel<2><<<NBUCK, 256, 0, stream>>>(Abuf, Zbuf, rec, off64,
                                              We + 320, be + 64,
                                              stats + 128, gamma, beta);
    mlp_kernel<1><<<NBUCK, 256, 0, stream>>>(Zbuf, W1 + 4096, b1 + 64,
                                             W2 + 4096, b2 + 64, stats + 256);

    // ---- GINE layer 3: T = BN+relu with stats2 ----
    aggb_kernel<2><<<NBUCK, 256, 0, stream>>>(Zbuf, Abuf, rec, off64,
                                              We + 640, be + 128,
                                              stats + 256, gamma, beta);
    mlp_kernel<1><<<NBUCK, 256, 0, stream>>>(Abuf, W1 + 8192, b1 + 128,
                                             W2 + 8192, b2 + 128, stats + 384);

    // ---- pooling + head (fused final BN+relu with stats3) ----
    head_kernel<<<NGRAPH, 128, 0, stream>>>(Abuf, Wl1, bl1, Wl2, bl2,
                                            (float*)d_out, stats + 384, gamma, beta);
}

// Round 7
// 1781.523 us; speedup vs baseline: 3.1300x; 3.1300x over previous
//
#include <hip/hip_runtime.h>
#include <hip/hip_bf16.h>

typedef __hip_bfloat16 bf16;
typedef __attribute__((ext_vector_type(8))) short short8;
typedef __attribute__((ext_vector_type(4))) float floatx4;

#define NNODES 118784
#define NEDGES 3000000
#define INDIM 116
#define EMBD 16
#define HID 64
#define NGRAPH 1024
#define ROIS 116

__device__ __forceinline__ float b2f(bf16 v) { return __bfloat162float(v); }
__device__ __forceinline__ bf16 f2b(float v) { return __float2bfloat16(v); }
__device__ __forceinline__ unsigned f2u(float v) {
    bf16 b = __float2bfloat16(v);
    return (unsigned)*reinterpret_cast<unsigned short*>(&b);
}
__device__ __forceinline__ float uf(unsigned u) { return __uint_as_float(u); }

// ---------------------------------------------------------------------------
// Sort phase 1: per-node in-degree histogram
// ---------------------------------------------------------------------------
__global__ __launch_bounds__(256) void hist_kernel(
    const int* __restrict__ dst, int* __restrict__ cnt)
{
    int i = blockIdx.x * 256 + threadIdx.x;
    if (i < NEDGES) atomicAdd(&cnt[dst[i]], 1);
}

// ---------------------------------------------------------------------------
// Sort phase 2: parallel exclusive scan (232 blocks x 512 elements)
// ---------------------------------------------------------------------------
__global__ __launch_bounds__(256) void scan1_kernel(
    const int* __restrict__ cnt, int* __restrict__ bsum)
{
    __shared__ int sd[256];
    const int b = blockIdx.x, t = threadIdx.x;
    sd[t] = cnt[b * 512 + t] + cnt[b * 512 + t + 256];
    __syncthreads();
    for (int s = 128; s > 0; s >>= 1) {
        if (t < s) sd[t] += sd[t + s];
        __syncthreads();
    }
    if (t == 0) bsum[b] = sd[0];
}

__global__ __launch_bounds__(256) void scan2_kernel(
    const int* __restrict__ bsum, int* __restrict__ boff, int* __restrict__ offN)
{
    __shared__ int sd[256];
    const int t = threadIdx.x;
    sd[t] = (t < 232) ? bsum[t] : 0;
    __syncthreads();
    for (int d = 1; d < 256; d <<= 1) {
        int v = (t >= d) ? sd[t - d] : 0;
        __syncthreads();
        sd[t] += v;
        __syncthreads();
    }
    if (t < 232) boff[t] = (t == 0) ? 0 : sd[t - 1];
    if (t == 0) offN[0] = NEDGES;     // off[NNODES]
}

__global__ __launch_bounds__(256) void scan3_kernel(
    const int* __restrict__ cnt, const int* __restrict__ boff,
    int* __restrict__ off, int* __restrict__ cur)
{
    __shared__ int sd[256];
    const int b = blockIdx.x, t = threadIdx.x;
    const int base = b * 512;
    const int c0 = cnt[base + 2 * t], c1 = cnt[base + 2 * t + 1];
    sd[t] = c0 + c1;
    __syncthreads();
    for (int d = 1; d < 256; d <<= 1) {
        int v = (t >= d) ? sd[t - d] : 0;
        __syncthreads();
        sd[t] += v;
        __syncthreads();
    }
    const int ex = ((t == 0) ? 0 : sd[t - 1]) + boff[b];
    off[base + 2 * t] = ex;           cur[base + 2 * t] = ex;
    off[base + 2 * t + 1] = ex + c0;  cur[base + 2 * t + 1] = ex + c0;
}

// ---------------------------------------------------------------------------
// Sort phase 3: place packed records at per-node offsets.
// record = {src, ea0|ea1<<16, ea2|ea3<<16, ea4}  (16B)
// ---------------------------------------------------------------------------
__global__ __launch_bounds__(256) void place_kernel(
    const int* __restrict__ src, const int* __restrict__ dst,
    const float* __restrict__ ea, int* __restrict__ cur,
    uint4* __restrict__ rec)
{
    const int e = blockIdx.x * 256 + threadIdx.x;
    if (e >= NEDGES) return;
    const float* a = ea + (size_t)e * 5;
    const unsigned m0 = f2u(a[0]) | (f2u(a[1]) << 16);
    const unsigned m1 = f2u(a[2]) | (f2u(a[3]) << 16);
    const unsigned m2 = f2u(a[4]);
    const int p = atomicAdd(&cur[dst[e]], 1);   // cur pre-seeded with off
    rec[p] = make_uint4((unsigned)src[e], m0, m1, m2);
}

// ---------------------------------------------------------------------------
// Encoder as MFMA GEMM (verified round 5/6)
// ---------------------------------------------------------------------------
__global__ __launch_bounds__(256) void enc_kernel(
    const float* __restrict__ x, const int* __restrict__ gid,
    const float* __restrict__ emb, const float* __restrict__ Wenc,
    const float* __restrict__ benc,
    bf16* __restrict__ hb, float* __restrict__ stats)
{
    __shared__ unsigned short Ap[4 * 5 * 64 * 8];
    __shared__ unsigned short Bp[4 * 5 * 64 * 8];

    const int tid = threadIdx.x;
    const int r0 = blockIdx.x * 64;

    for (int i = tid; i < 64 * INDIM; i += 256) {
        const int r = i / INDIM, k = i - r * INDIM;
        const float v = x[(size_t)(r0 + r) * INDIM + k];
        const int g = r >> 4, m = r & 15, s = k >> 5, q = (k >> 3) & 3, j = k & 7;
        Ap[(((g * 5 + s) * 64) + q * 16 + m) * 8 + j] = (unsigned short)f2u(v);
    }
    for (int i = tid; i < 64 * EMBD; i += 256) {
        const int r = i >> 4, kk = i & 15, k = INDIM + kk;
        const float v = emb[gid[r0 + r] * EMBD + kk];
        const int g = r >> 4, m = r & 15, s = k >> 5, q = (k >> 3) & 3, j = k & 7;
        Ap[(((g * 5 + s) * 64) + q * 16 + m) * 8 + j] = (unsigned short)f2u(v);
    }
    for (int i = tid; i < 64 * 28; i += 256) {
        const int r = i / 28, k = 132 + (i - r * 28);
        const int g = r >> 4, m = r & 15, s = k >> 5, q = (k >> 3) & 3, j = k & 7;
        Ap[(((g * 5 + s) * 64) + q * 16 + m) * 8 + j] = 0;
    }
    for (int i = tid; i < 132 * 64; i += 256) {
        const int k = i >> 6, n = i & 63;
        const float v = Wenc[i];
        const int c = n >> 4, m = n & 15, s = k >> 5, q = (k >> 3) & 3, j = k & 7;
        Bp[(((c * 5 + s) * 64) + q * 16 + m) * 8 + j] = (unsigned short)f2u(v);
    }
    for (int i = tid; i < 28 * 64; i += 256) {
        const int k = 132 + (i >> 6), n = i & 63;
        const int c = n >> 4, m = n & 15, s = k >> 5, q = (k >> 3) & 3, j = k & 7;
        Bp[(((c * 5 + s) * 64) + q * 16 + m) * 8 + j] = 0;
    }
    __syncthreads();

    const int lane = tid & 63;
    const int wv   = tid >> 6;
    const int m    = lane & 15;
    const int q    = lane >> 4;

    floatx4 acc[4];
    #pragma unroll
    for (int c = 0; c < 4; c++) acc[c] = {0.f, 0.f, 0.f, 0.f};

    #pragma unroll
    for (int s = 0; s < 5; s++) {
        short8 af = *(const short8*)&Ap[((wv * 5 + s) * 64 + lane) * 8];
        #pragma unroll
        for (int c = 0; c < 4; c++) {
            short8 bfr = *(const short8*)&Bp[((c * 5 + s) * 64 + lane) * 8];
            acc[c] = __builtin_amdgcn_mfma_f32_16x16x32_bf16(af, bfr, acc[c], 0, 0, 0);
        }
    }

    #pragma unroll
    for (int c = 0; c < 4; c++) {
        const int ch = c * 16 + m;
        const float bb = benc[ch];
        float sv = 0.f, sq = 0.f;
        #pragma unroll
        for (int r = 0; r < 4; r++) {
            const int row = r0 + wv * 16 + q * 4 + r;
            float a = fmaxf(acc[c][r] + bb, 0.f);
            hb[(size_t)row * HID + ch] = f2b(a);
            sv += a; sq += a * a;
        }
        sv += __shfl_xor(sv, 16); sv += __shfl_xor(sv, 32);
        sq += __shfl_xor(sq, 16); sq += __shfl_xor(sq, 32);
        if (q == 0) {
            unsafeAtomicAdd(&stats[ch], sv);
            unsafeAtomicAdd(&stats[64 + ch], sq);
        }
    }
}

// ---------------------------------------------------------------------------
// Gather-aggregate, wave per node, 8-deep pipeline, fused BN-on-read.
// MODE: 0 = identity, 1 = BN, 2 = BN + relu  (applied to hin reads)
// z[n] = T(h[n]) + sum_{e->n} relu(T(h[src]) + ea@We + be)
// ---------------------------------------------------------------------------
template <int MODE>
__global__ __launch_bounds__(256) void agg_kernel(
    const bf16* __restrict__ hin, bf16* __restrict__ zout,
    const uint4* __restrict__ rec, const int* __restrict__ off,
    const float* __restrict__ We, const float* __restrict__ be,
    const float* __restrict__ stats, const float* __restrict__ gamma,
    const float* __restrict__ beta)
{
    const int lane = threadIdx.x & 63;
    const int node = (blockIdx.x * 256 + threadIdx.x) >> 6;
    if (node >= NNODES) return;

    float gg = 1.f, bbt = 0.f;
    if (MODE != 0) {
        const float m = stats[lane] * (1.f / NNODES);
        const float var = stats[64 + lane] * (1.f / NNODES) - m * m;
        const float inv = rsqrtf(var + 1e-5f);
        gg = gamma[lane] * inv;
        bbt = beta[lane] - gg * m;
    }
    const float w0 = We[lane], w1 = We[64 + lane], w2 = We[128 + lane];
    const float w3 = We[192 + lane], w4 = We[256 + lane];
    const float bel = be[lane];

    const int s0 = off[node];
    const int s1 = off[node + 1];

    float self = b2f(hin[(size_t)node * HID + lane]);
    if (MODE == 1) self = gg * self + bbt;
    if (MODE == 2) self = fmaxf(gg * self + bbt, 0.f);

    float acc = 0.f;
    int i = s0;
    // 8-deep gather pipeline: 8 record broadcasts + 8 row gathers in flight
    for (; i + 8 <= s1; i += 8) {
        uint4 r[8];
        #pragma unroll
        for (int j = 0; j < 8; j++) r[j] = rec[i + j];
        float h[8];
        #pragma unroll
        for (int j = 0; j < 8; j++)
            h[j] = b2f(hin[(size_t)r[j].x * HID + lane]);
        #pragma unroll
        for (int j = 0; j < 8; j++) {
            float hh = h[j];
            if (MODE == 1) hh = gg * hh + bbt;
            if (MODE == 2) hh = fmaxf(gg * hh + bbt, 0.f);
            const float v = bel
                + uf(r[j].y << 16) * w0 + uf(r[j].y & 0xFFFF0000u) * w1
                + uf(r[j].z << 16) * w2 + uf(r[j].z & 0xFFFF0000u) * w3
                + uf(r[j].w << 16) * w4 + hh;
            acc += fmaxf(v, 0.f);
        }
    }
    for (; i + 4 <= s1; i += 4) {
        uint4 r[4];
        #pragma unroll
        for (int j = 0; j < 4; j++) r[j] = rec[i + j];
        float h[4];
        #pragma unroll
        for (int j = 0; j < 4; j++)
            h[j] = b2f(hin[(size_t)r[j].x * HID + lane]);
        #pragma unroll
        for (int j = 0; j < 4; j++) {
            float hh = h[j];
            if (MODE == 1) hh = gg * hh + bbt;
            if (MODE == 2) hh = fmaxf(gg * hh + bbt, 0.f);
            const float v = bel
                + uf(r[j].y << 16) * w0 + uf(r[j].y & 0xFFFF0000u) * w1
                + uf(r[j].z << 16) * w2 + uf(r[j].z & 0xFFFF0000u) * w3
                + uf(r[j].w << 16) * w4 + hh;
            acc += fmaxf(v, 0.f);
        }
    }
    for (; i < s1; i++) {
        const uint4 r = rec[i];
        float hh = b2f(hin[(size_t)r.x * HID + lane]);
        if (MODE == 1) hh = gg * hh + bbt;
        if (MODE == 2) hh = fmaxf(gg * hh + bbt, 0.f);
        const float v = bel
            + uf(r.y << 16) * w0 + uf(r.y & 0xFFFF0000u) * w1
            + uf(r.z << 16) * w2 + uf(r.z & 0xFFFF0000u) * w3
            + uf(r.w << 16) * w4 + hh;
        acc += fmaxf(v, 0.f);
    }

    zout[(size_t)node * HID + lane] = f2b(self + acc);
}

// ---------------------------------------------------------------------------
// Node MLP via MFMA, in place on Z (verified round 5/6)
// MODE 0: z <- relu(o).  MODE 1: z <- o (pre-BN) + stats.
// ---------------------------------------------------------------------------
template <int MODE>
__global__ __launch_bounds__(256) void mlp_kernel(
    bf16* __restrict__ Zg,
    const float* __restrict__ W1, const float* __restrict__ b1,
    const float* __restrict__ W2, const float* __restrict__ b2,
    float* __restrict__ stats)
{
    __shared__ unsigned short Zl[64 * 72];
    __shared__ unsigned short W1t[64 * 72];
    __shared__ unsigned short W2t[64 * 72];
    __shared__ unsigned short Tl[64 * 72];

    const int tid = threadIdx.x;
    const int r0 = blockIdx.x * 64;

    for (int i = tid; i < 4096; i += 256) {
        int k = i >> 6, n = i & 63;
        W1t[n * 72 + k] = (unsigned short)f2u(W1[i]);
        W2t[n * 72 + k] = (unsigned short)f2u(W2[i]);
    }
    {
        const uint4* zg = (const uint4*)(Zg + (size_t)r0 * HID);
        for (int i = tid; i < 512; i += 256) {
            int row = i >> 3, ch = i & 7;
            uint4 v = zg[row * 8 + ch];
            *(uint4*)&Zl[row * 72 + ch * 8] = v;
        }
    }
    __syncthreads();

    const int lane = tid & 63;
    const int wv   = tid >> 6;
    const int m    = lane & 15;
    const int q    = lane >> 4;
    const int mrow = wv * 16;

    float bias1[4], bias2[4];
    #pragma unroll
    for (int c = 0; c < 4; c++) {
        bias1[c] = b1[c * 16 + m];
        bias2[c] = b2[c * 16 + m];
    }

    floatx4 acc[4];
    #pragma unroll
    for (int c = 0; c < 4; c++) acc[c] = {0.f, 0.f, 0.f, 0.f};
    #pragma unroll
    for (int s = 0; s < 2; s++) {
        short8 af = *(const short8*)&Zl[(mrow + m) * 72 + s * 32 + q * 8];
        #pragma unroll
        for (int c = 0; c < 4; c++) {
            short8 bfr = *(const short8*)&W1t[(c * 16 + m) * 72 + s * 32 + q * 8];
            acc[c] = __builtin_amdgcn_mfma_f32_16x16x32_bf16(af, bfr, acc[c], 0, 0, 0);
        }
    }
    #pragma unroll
    for (int c = 0; c < 4; c++)
        #pragma unroll
        for (int r = 0; r < 4; r++)
            Tl[(mrow + q * 4 + r) * 72 + c * 16 + m] =
                (unsigned short)f2u(fmaxf(acc[c][r] + bias1[c], 0.f));
    __syncthreads();

    #pragma unroll
    for (int c = 0; c < 4; c++) acc[c] = {0.f, 0.f, 0.f, 0.f};
    #pragma unroll
    for (int s = 0; s < 2; s++) {
        short8 af = *(const short8*)&Tl[(mrow + m) * 72 + s * 32 + q * 8];
        #pragma unroll
        for (int c = 0; c < 4; c++) {
            short8 bfr = *(const short8*)&W2t[(c * 16 + m) * 72 + s * 32 + q * 8];
            acc[c] = __builtin_amdgcn_mfma_f32_16x16x32_bf16(af, bfr, acc[c], 0, 0, 0);
        }
    }
    #pragma unroll
    for (int c = 0; c < 4; c++) {
        float sv = 0.f, sq = 0.f;
        #pragma unroll
        for (int r = 0; r < 4; r++) {
            float o = acc[c][r] + bias2[c];
            if (MODE == 0) o = fmaxf(o, 0.f);
            Zg[(size_t)(r0 + mrow + q * 4 + r) * HID + c * 16 + m] = f2b(o);
            if (MODE == 1) { sv += o; sq += o * o; }
        }
        if (MODE == 1) {
            sv += __shfl_xor(sv, 16); sv += __shfl_xor(sv, 32);
            sq += __shfl_xor(sq, 16); sq += __shfl_xor(sq, 32);
            if (q == 0) {
                unsafeAtomicAdd(&stats[c * 16 + m], sv);
                unsafeAtomicAdd(&stats[64 + c * 16 + m], sq);
            }
        }
    }
}

// ---------------------------------------------------------------------------
// Head with fused final BN+relu (verified round 6)
// ---------------------------------------------------------------------------
__global__ __launch_bounds__(128) void head_kernel(
    const bf16* __restrict__ hb, const float* __restrict__ Wl1,
    const float* __restrict__ bl1, const float* __restrict__ Wl2,
    const float* __restrict__ bl2, float* __restrict__ out,
    const float* __restrict__ stats, const float* __restrict__ gamma,
    const float* __restrict__ beta)
{
    __shared__ float part[2 * HID];
    __shared__ float ps[HID];
    __shared__ float r0[128], r1[128];

    const int g = blockIdx.x;
    const int tid = threadIdx.x;
    const int lane = tid & 63;
    const int wv = tid >> 6;
    const bf16* hbg = hb + (size_t)g * ROIS * HID;

    const float mm = stats[lane] * (1.f / NNODES);
    const float var = stats[64 + lane] * (1.f / NNODES) - mm * mm;
    const float inv = rsqrtf(var + 1e-5f);
    const float gg = gamma[lane] * inv;
    const float bbt = beta[lane] - gg * mm;

    float acc = 0.f;
    for (int r = wv; r < ROIS; r += 2)
        acc += fmaxf(gg * b2f(hbg[r * HID + lane]) + bbt, 0.f);
    part[wv * HID + lane] = acc;
    __syncthreads();
    if (tid < HID) ps[tid] = fmaxf(part[tid] + part[HID + tid], 0.f);
    __syncthreads();

    float e0 = 0.f, e1 = 0.f;
    if (tid < ROIS) {
        float a = bl1[tid];
        #pragma unroll 8
        for (int c = 0; c < HID; c++)
            a += ps[c] * Wl1[c * ROIS + tid];
        e0 = a * Wl2[tid * 2 + 0];
        e1 = a * Wl2[tid * 2 + 1];
    }
    r0[tid] = e0;
    r1[tid] = e1;
    __syncthreads();
    for (int s = 64; s > 0; s >>= 1) {
        if (tid < s) { r0[tid] += r0[tid + s]; r1[tid] += r1[tid + s]; }
        __syncthreads();
    }
    if (tid == 0) {
        out[g * 2 + 0] = r0[0] + bl2[0];
        out[g * 2 + 1] = r1[0] + bl2[1];
    }
}

// ---------------------------------------------------------------------------
extern "C" void kernel_launch(void* const* d_in, const int* in_sizes, int n_in,
                              void* d_out, int out_size, void* d_ws, size_t ws_size,
                              hipStream_t stream)
{
    const float* x       = (const float*)d_in[0];
    const float* ea      = (const float*)d_in[1];
    const int*   eidx    = (const int*)  d_in[2];
    const int*   gid     = (const int*)  d_in[4];
    const float* emb     = (const float*)d_in[5];
    const float* Wenc    = (const float*)d_in[6];
    const float* benc    = (const float*)d_in[7];
    const float* gamma_e = (const float*)d_in[8];
    const float* beta_e  = (const float*)d_in[9];
    const float* We0     = (const float*)d_in[10];
    const float* be0     = (const float*)d_in[11];
    const float* W10     = (const float*)d_in[12];
    const float* b10     = (const float*)d_in[13];
    const float* W20     = (const float*)d_in[14];
    const float* b20     = (const float*)d_in[15];
    const float* We      = (const float*)d_in[16];
    const float* be      = (const float*)d_in[17];
    const float* W1      = (const float*)d_in[18];
    const float* b1      = (const float*)d_in[19];
    const float* W2      = (const float*)d_in[20];
    const float* b2      = (const float*)d_in[21];
    const float* gamma   = (const float*)d_in[22];
    const float* beta    = (const float*)d_in[23];
    const float* Wl1     = (const float*)d_in[24];
    const float* bl1     = (const float*)d_in[25];
    const float* Wl2     = (const float*)d_in[26];
    const float* bl2     = (const float*)d_in[27];

    const int* srcp = eidx;
    const int* dstp = eidx + NEDGES;

    // workspace (~80.2 MB, <= 91.2 MB proven available in round 3):
    // A | Z | rec (16B*E) | cnt | off | cur | bsum | boff | stats
    const size_t NH = (size_t)NNODES * HID;
    char* p = (char*)d_ws;
    bf16*  Abuf = (bf16*)p;  p += NH * 2;
    bf16*  Zbuf = (bf16*)p;  p += NH * 2;
    uint4* rec  = (uint4*)p; p += (size_t)NEDGES * 16;
    int* cnt    = (int*)p;   p += (size_t)NNODES * 4;
    int* off    = (int*)p;   p += (size_t)(NNODES + 16) * 4;
    int* cur    = (int*)p;   p += (size_t)NNODES * 4;
    int* bsum   = (int*)p;   p += 256 * 4;
    int* boff   = (int*)p;   p += 256 * 4;
    float* stats = (float*)p;                  // 512 floats

    hipMemsetAsync(cnt, 0, (size_t)NNODES * 4, stream);
    hipMemsetAsync(stats, 0, 512 * 4, stream);

    const int eb = (NEDGES + 255) / 256;       // 11719
    const int nb = (NNODES * HID + 255) / 256; // 29696 (exact)

    // ---- sort edges by dst node (packed records) ----
    hist_kernel<<<eb, 256, 0, stream>>>(dstp, cnt);
    scan1_kernel<<<232, 256, 0, stream>>>(cnt, bsum);
    scan2_kernel<<<1, 256, 0, stream>>>(bsum, boff, off + NNODES);
    scan3_kernel<<<232, 256, 0, stream>>>(cnt, boff, off, cur);
    place_kernel<<<eb, 256, 0, stream>>>(srcp, dstp, ea, cur, rec);

    // ---- encoder (pre-BN + stats0) ----
    enc_kernel<<<NNODES / 64, 256, 0, stream>>>(x, gid, emb, Wenc, benc, Abuf, stats);

    // ---- GINE layer 0: T = BN_e (no relu); mlp relu ----
    agg_kernel<1><<<nb, 256, 0, stream>>>(Abuf, Zbuf, rec, off, We0, be0,
                                          stats, gamma_e, beta_e);
    mlp_kernel<0><<<NNODES / 64, 256, 0, stream>>>(Zbuf, W10, b10, W20, b20, nullptr);

    // ---- GINE layer 1: identity T (input already relu'd); stats1 ----
    agg_kernel<0><<<nb, 256, 0, stream>>>(Zbuf, Abuf, rec, off, We, be,
                                          nullptr, nullptr, nullptr);
    mlp_kernel<1><<<NNODES / 64, 256, 0, stream>>>(Abuf, W1, b1, W2, b2, stats + 128);

    // ---- GINE layer 2: T = BN+relu (stats1); stats2 ----
    agg_kernel<2><<<nb, 256, 0, stream>>>(Abuf, Zbuf, rec, off,
                                          We + 320, be + 64,
                                          stats + 128, gamma, beta);
    mlp_kernel<1><<<NNODES / 64, 256, 0, stream>>>(Zbuf, W1 + 4096, b1 + 64,
                                                   W2 + 4096, b2 + 64, stats + 256);

    // ---- GINE layer 3: T = BN+relu (stats2); stats3 ----
    agg_kernel<2><<<nb, 256, 0, stream>>>(Zbuf, Abuf, rec, off,
                                          We + 640, be + 128,
                                          stats + 256, gamma, beta);
    mlp_kernel<1><<<NNODES / 64, 256, 0, stream>>>(Abuf, W1 + 8192, b1 + 128,
                                                   W2 + 8192, b2 + 128, stats + 384);

    // ---- pooling + head (fused final BN+relu, stats3) ----
    head_kernel<<<NGRAPH, 128, 0, stream>>>(Abuf, Wl1, bl1, Wl2, bl2,
                                            (float*)d_out, stats + 384, gamma, beta);
}